// Round 18
// baseline (137.085 us; speedup 1.0000x reference)
//
#include <hip/hip_runtime.h>

typedef _Float16 f16;
typedef __attribute__((ext_vector_type(8))) _Float16 f16x8;
typedef __attribute__((ext_vector_type(4))) _Float16 f16x4;
typedef __attribute__((ext_vector_type(4))) float f32x4;

// Barrier that does NOT drain vmcnt: LDS ordering via lgkmcnt(0).
#define BARRIER()                                              \
    do {                                                       \
        asm volatile("s_waitcnt lgkmcnt(0)" ::: "memory");     \
        __builtin_amdgcn_s_barrier();                          \
        __builtin_amdgcn_sched_barrier(0);                     \
    } while (0)

namespace {
constexpr int kL   = 65536;
constexpr int kR   = 256;
constexpr int kD   = 64;
constexpr int kDV  = 64;

constexpr int kChunks  = 4;     // 64-col chunks per block
constexpr int kABlocks = 256;   // 256 cols each
constexpr int kBBlocks = 256;   // 256 cols each

constexpr float kBc   = 0.7745966692414834f;      // sqrt(0.6)
constexpr float kBase0 = -1.1417405264f;          // 0.1 + ln(0.6^16 * 2^10)
constexpr float kOutScale = 9.5367431640625e-7f;  // 2^-20 undoes PHI_SCALE^2
}

// ---------------------------------------------------------------------------
// Kernel A: kvAcc[dv][r] (f32) += (phi(K_cols)*2^10 @ V_cols)^T via atomics.
// Block 0 additionally packs W into f16 fragment order (Wp) for kernel B.
// Single barrier per chunk: {pv(c-1) | zphi(c) | stage(c+1) | issue(c+2)} BAR
// ---------------------------------------------------------------------------
__global__ __launch_bounds__(512, 2)
void favor_kv(const float* __restrict__ Kg, const float* __restrict__ Vg,
              const float* __restrict__ Wg, float* __restrict__ kvAcc,
              f16* __restrict__ Wp)
{
    __shared__ f16 sXt[2][64 * 64];    // K chunk [l][d], swizzled, dbuf
    __shared__ f16 sVt[3][64 * 64];    // V chunk [dv][l], swizzled, 3-buf
    __shared__ f16 sPhi[2][256 * 64];  // [r][l], swizzled, dbuf
    __shared__ float sRed[2][8 * 64];
    __shared__ float sRedT[2][64];

    const int tid  = threadIdx.x;
    const int w    = tid >> 6;
    const int lane = tid & 63;
    const int l15  = lane & 15;
    const int lhi  = lane >> 4;
    const int blk  = blockIdx.x;
    const int lblk = blk * (64 * kChunks);

    const int scol  = lane;
    const int dbase = w * 8;
    const int wr = w >> 1;
    const int wc = w & 1;

    // ---- block 0: pack W -> Wp (fragment order) for kernel B
    if (blk == 0) {
#pragma unroll
        for (int it = 0; it < 4; ++it) {
            const int idx    = tid + it * 512;      // 0..2047
            const int fragid = idx >> 6;            // rf*2+ks
            const int ln     = idx & 63;
            const int rf = fragid >> 1, ks = fragid & 1;
            const float* src = Wg + (16 * rf + (ln & 15)) * kD + 32 * ks + 8 * (ln >> 4);
            f16x8 v;
#pragma unroll
            for (int j = 0; j < 8; ++j) v[j] = (f16)src[j];
            *(f16x8*)&Wp[(size_t)idx * 8] = v;
        }
    }

    // rolling register buffers (depth 2)
    float ka[2][8], va[2][8];
    auto issueLoads = [&](int c) {
        const int l0 = lblk + c * 64;
        const int p  = c & 1;
#pragma unroll
        for (int j = 0; j < 8; ++j) ka[p][j] = Kg[(dbase + j) * kL + l0 + scol];
#pragma unroll
        for (int j = 0; j < 8; ++j) va[p][j] = Vg[(size_t)(l0 + dbase + j) * kDV + scol];
    };

    issueLoads(0);
    issueLoads(1);

    f16x8 wfrag[2][2];  // B-operand: col = l15 -> r, k = 8*lhi+j -> d
#pragma unroll
    for (int ri = 0; ri < 2; ++ri)
#pragma unroll
        for (int ks = 0; ks < 2; ++ks) {
            const float* p = Wg + (32 * w + 16 * ri + l15) * kD + 32 * ks + 8 * lhi;
            f16x8 v;
#pragma unroll
            for (int j = 0; j < 8; ++j) v[j] = (f16)p[j];
            wfrag[ri][ks] = v;
        }

    f32x4 acc[4][2];
#pragma unroll
    for (int a = 0; a < 4; ++a)
#pragma unroll
        for (int d = 0; d < 2; ++d) { f32x4 z0 = {0.f, 0.f, 0.f, 0.f}; acc[a][d] = z0; }

    auto stage = [&](int c) {
        const int p  = c & 1;
        const int pv3 = c % 3;
        float s = 0.f;
        f16x8 hk, hv;
#pragma unroll
        for (int j = 0; j < 8; ++j) {
            const float x = ka[p][j];
            s += x * x;
            hk[j] = (f16)x;
            hv[j] = (f16)va[p][j];
        }
        sRed[p][w * 64 + scol] = s;
        *(f16x8*)&sXt[p][scol * 64 + (dbase ^ ((scol & 7) << 3))] = hk;
        *(f16x8*)&sVt[pv3][scol * 64 + (dbase ^ ((scol & 7) << 3))] = hv;
    };

    auto norms = [&](int c) {
        const int p = c & 1;
        float sqv = 0.f;
#pragma unroll
        for (int g = 0; g < 8; ++g) sqv += sRed[p][g * 64 + lane];
        sRedT[p][lane] = sqv;
    };

    auto zphi = [&](int c) {
        const int p = c & 1;
        f16x8 bfr[2][4];
#pragma unroll
        for (int ks = 0; ks < 2; ++ks)
#pragma unroll
            for (int lf = 0; lf < 4; ++lf) {
                const int row = 16 * lf + l15;
                bfr[ks][lf] = *(const f16x8*)&sXt[p][row * 64 + ((32 * ks + 8 * lhi) ^ ((row & 7) << 3))];
            }
#pragma unroll
        for (int ri = 0; ri < 2; ++ri) {
            f32x4 z[4];
#pragma unroll
            for (int lf = 0; lf < 4; ++lf) { f32x4 z0 = {0.f, 0.f, 0.f, 0.f}; z[lf] = z0; }
            __builtin_amdgcn_s_setprio(1);
#pragma unroll
            for (int ks = 0; ks < 2; ++ks)
#pragma unroll
                for (int lf = 0; lf < 4; ++lf)
                    z[lf] = __builtin_amdgcn_mfma_f32_16x16x32_f16(bfr[ks][lf], wfrag[ri][ks], z[lf], 0, 0, 0);
            __builtin_amdgcn_s_setprio(0);
            const int r = 32 * w + 16 * ri + l15;
#pragma unroll
            for (int lf = 0; lf < 4; ++lf) {
                const f32x4 sq4 = *(const f32x4*)&sRedT[p][16 * lf + 4 * lhi];
                f16x4 ph;
#pragma unroll
                for (int j = 0; j < 4; ++j)
                    ph[j] = (f16)__expf(fmaf(z[lf][j], kBc, kBase0 - sq4[j]));
                const int lbase = 16 * lf + 4 * lhi;
                *(f16x4*)&sPhi[p][r * 64 + (lbase ^ ((r & 7) << 3))] = ph;
            }
        }
    };

    auto pv = [&](int c) {
        const int p  = c & 1;
        const int pv3 = c % 3;
        __builtin_amdgcn_s_setprio(1);
#pragma unroll
        for (int ks = 0; ks < 2; ++ks) {
            f16x8 af[4], bf[2];
#pragma unroll
            for (int ai = 0; ai < 4; ++ai) {
                const int r = 64 * wr + 16 * ai + l15;
                af[ai] = *(const f16x8*)&sPhi[p][r * 64 + ((32 * ks + 8 * lhi) ^ ((r & 7) << 3))];
            }
#pragma unroll
            for (int di = 0; di < 2; ++di) {
                const int dv = 32 * wc + 16 * di + l15;
                bf[di] = *(const f16x8*)&sVt[pv3][dv * 64 + ((32 * ks + 8 * lhi) ^ ((dv & 7) << 3))];
            }
#pragma unroll
            for (int ai = 0; ai < 4; ++ai)
#pragma unroll
                for (int di = 0; di < 2; ++di)
                    acc[ai][di] = __builtin_amdgcn_mfma_f32_16x16x32_f16(af[ai], bf[di], acc[ai][di], 0, 0, 0);
        }
        __builtin_amdgcn_s_setprio(0);
    };

    stage(0);
    BARRIER();
#pragma unroll
    for (int c = 0; c < kChunks; ++c) {
        if (c > 0) pv(c - 1);
        norms(c);
        zphi(c);
        if (c + 1 < kChunks) stage(c + 1);
        if (c + 2 < kChunks) issueLoads(c + 2);
        BARRIER();
    }
    pv(kChunks - 1);

    // ---- accumulate per-block kv contribution into f32 kvAcc[dv][r]
#pragma unroll
    for (int ai = 0; ai < 4; ++ai)
#pragma unroll
        for (int di = 0; di < 2; ++di) {
            const int dv = 32 * wc + 16 * di + l15;
            const int rb = 64 * wr + 16 * ai + 4 * lhi;
#pragma unroll
            for (int j = 0; j < 4; ++j)
                atomicAdd(&kvAcc[dv * kR + rb + j], acc[ai][di][j]);
        }
}

// ---------------------------------------------------------------------------
// Kernel B: out = (phi(Q)*2^10)^T @ kv, scaled 2^-20.
// kv read from f32 kvAcc (converted to f16 fragments in prologue); W via Wp.
// Single barrier per chunk; sPhiT double-buffered.
// ---------------------------------------------------------------------------
__global__ __launch_bounds__(512, 2)
void favor_out(const float* __restrict__ Qg, const f16* __restrict__ Wp,
               const float* __restrict__ kvAcc, float* __restrict__ outg)
{
    __shared__ f16 sXt[2][64 * 64];    // Q chunk [l][d], swizzled, dbuf
    __shared__ f16 sPhiT[2][64 * 256]; // [l][r], swizzled, dbuf
    __shared__ float sRed[2][8 * 64];

    const int tid  = threadIdx.x;
    const int w    = tid >> 6;
    const int lane = tid & 63;
    const int l15  = lane & 15;
    const int lhi  = lane >> 4;
    const int blk  = blockIdx.x;
    const int lblk = blk * (64 * kChunks);

    const int scol  = lane;
    const int dbase = w * 8;
    const int lfo = w >> 1;
    const int dvh = w & 1;

    float qa[2][8];
    auto issueLoads = [&](int c) {
        const int l0 = lblk + c * 64;
        const int p  = c & 1;
#pragma unroll
        for (int j = 0; j < 8; ++j) qa[p][j] = Qg[(dbase + j) * kL + l0 + scol];
    };

    issueLoads(0);
    issueLoads(1);

    // kv B-fragments (rows dv, k = r) from f32 accumulator, cvt once
    f16x8 kvf[2][8];
#pragma unroll
    for (int di = 0; di < 2; ++di) {
        const int dv = 32 * dvh + 16 * di + l15;
#pragma unroll
        for (int ks = 0; ks < 8; ++ks) {
            const float* src = kvAcc + dv * kR + 32 * ks + 8 * lhi;
            f16x8 h;
#pragma unroll
            for (int j = 0; j < 8; ++j) h[j] = (f16)src[j];
            kvf[di][ks] = h;
        }
    }

    f16x8 wfrag[2][2];  // A-operand for wave w's r rows 32w+16ri (packed)
#pragma unroll
    for (int ri = 0; ri < 2; ++ri)
#pragma unroll
        for (int ks = 0; ks < 2; ++ks)
            wfrag[ri][ks] = *(const f16x8*)&Wp[(size_t)((((2 * w + ri) * 2 + ks) * 64) + lane) * 8];

    auto stageQ = [&](int c) {
        const int p = c & 1;
        float s = 0.f;
        f16x8 hq;
#pragma unroll
        for (int j = 0; j < 8; ++j) {
            const float x = qa[p][j];
            s += x * x;
            hq[j] = (f16)x;
        }
        sRed[p][w * 64 + scol] = s;
        *(f16x8*)&sXt[p][scol * 64 + (dbase ^ ((scol & 7) << 3))] = hq;
    };

    auto zphiQ = [&](int c) {
        const int p = c & 1;
        float sqv = 0.f;
#pragma unroll
        for (int g = 0; g < 8; ++g) sqv += sRed[p][g * 64 + lane];
        float tbase[4];
#pragma unroll
        for (int lf = 0; lf < 4; ++lf)
            tbase[lf] = kBase0 - __shfl(sqv, lf * 16 + l15, 64);

        f16x8 bfr[2][4];
#pragma unroll
        for (int ks = 0; ks < 2; ++ks)
#pragma unroll
            for (int lf = 0; lf < 4; ++lf) {
                const int row = 16 * lf + l15;
                bfr[ks][lf] = *(const f16x8*)&sXt[p][row * 64 + ((32 * ks + 8 * lhi) ^ ((row & 7) << 3))];
            }
#pragma unroll
        for (int ri = 0; ri < 2; ++ri) {
            f32x4 z[4];
#pragma unroll
            for (int lf = 0; lf < 4; ++lf) { f32x4 z0 = {0.f, 0.f, 0.f, 0.f}; z[lf] = z0; }
            __builtin_amdgcn_s_setprio(1);
#pragma unroll
            for (int ks = 0; ks < 2; ++ks)
#pragma unroll
                for (int lf = 0; lf < 4; ++lf)
                    z[lf] = __builtin_amdgcn_mfma_f32_16x16x32_f16(wfrag[ri][ks], bfr[ks][lf], z[lf], 0, 0, 0);
            __builtin_amdgcn_s_setprio(0);
            const int r0 = 32 * w + 16 * ri + 4 * lhi;
#pragma unroll
            for (int lf = 0; lf < 4; ++lf) {
                const int lc = 16 * lf + l15;
                f16x4 ph;
#pragma unroll
                for (int j = 0; j < 4; ++j)
                    ph[j] = (f16)__expf(fmaf(z[lf][j], kBc, tbase[lf]));
                *(f16x4*)&sPhiT[p][lc * 256 + (r0 ^ ((lc & 7) << 3))] = ph;
            }
        }
    };

    auto pvOut = [&](int c) {
        const int p = c & 1;
        f32x4 oA[2], oB[2];
        { f32x4 z0 = {0.f, 0.f, 0.f, 0.f}; oA[0] = z0; oA[1] = z0; oB[0] = z0; oB[1] = z0; }
        const int lrow = 16 * lfo + l15;
        __builtin_amdgcn_s_setprio(1);
#pragma unroll
        for (int ks = 0; ks < 4; ++ks) {
            const f16x8 afA = *(const f16x8*)&sPhiT[p][lrow * 256 + ((32 * ks + 8 * lhi) ^ ((lrow & 7) << 3))];
            const f16x8 afB = *(const f16x8*)&sPhiT[p][lrow * 256 + ((32 * (ks + 4) + 8 * lhi) ^ ((lrow & 7) << 3))];
#pragma unroll
            for (int di = 0; di < 2; ++di) {
                oA[di] = __builtin_amdgcn_mfma_f32_16x16x32_f16(afA, kvf[di][ks], oA[di], 0, 0, 0);
                oB[di] = __builtin_amdgcn_mfma_f32_16x16x32_f16(afB, kvf[di][ks + 4], oB[di], 0, 0, 0);
            }
        }
        __builtin_amdgcn_s_setprio(0);
        const int l0 = lblk + c * 64;
#pragma unroll
        for (int di = 0; di < 2; ++di) {
            const f32x4 o2 = oA[di] + oB[di];
#pragma unroll
            for (int j = 0; j < 4; ++j) {
                const int ll = 16 * lfo + 4 * lhi + j;
                const int dv = 32 * dvh + 16 * di + l15;
                outg[(size_t)(l0 + ll) * kDV + dv] = o2[j] * kOutScale;
            }
        }
    };

    stageQ(0);
    BARRIER();
#pragma unroll
    for (int c = 0; c < kChunks; ++c) {
        if (c > 0) pvOut(c - 1);
        zphiQ(c);
        if (c + 1 < kChunks) stageQ(c + 1);
        if (c + 2 < kChunks) issueLoads(c + 2);
        BARRIER();
    }
    pvOut(kChunks - 1);
}

extern "C" void kernel_launch(void* const* d_in, const int* in_sizes, int n_in,
                              void* d_out, int out_size, void* d_ws, size_t ws_size,
                              hipStream_t stream)
{
    const float* Q = (const float*)d_in[0];
    const float* K = (const float*)d_in[1];
    const float* V = (const float*)d_in[2];
    const float* W = (const float*)d_in[3];
    float* out = (float*)d_out;

    float* kvAcc = (float*)d_ws;                       // 256*64 f32 = 64 KiB
    f16* Wp = (f16*)((char*)d_ws + (size_t)kR * kDV * sizeof(float));  // 32 KiB

    hipMemsetAsync(kvAcc, 0, (size_t)kR * kDV * sizeof(float), stream);
    favor_kv<<<kABlocks, 512, 0, stream>>>(K, V, W, kvAcc, Wp);
    favor_out<<<kBBlocks, 512, 0, stream>>>(Q, Wp, kvAcc, out);

    (void)in_sizes; (void)n_in; (void)out_size; (void)ws_size;
}

// Round 19
// 35.704 us; speedup vs baseline: 3.8394x; 3.8394x over previous
//
#include <hip/hip_runtime.h>

typedef _Float16 f16;
typedef __attribute__((ext_vector_type(8))) _Float16 f16x8;
typedef __attribute__((ext_vector_type(4))) _Float16 f16x4;
typedef __attribute__((ext_vector_type(4))) float f32x4;

// Barrier that does NOT drain vmcnt: LDS ordering via lgkmcnt(0).
#define BARRIER()                                              \
    do {                                                       \
        asm volatile("s_waitcnt lgkmcnt(0)" ::: "memory");     \
        __builtin_amdgcn_s_barrier();                          \
        __builtin_amdgcn_sched_barrier(0);                     \
    } while (0)

namespace {
constexpr int kL   = 65536;
constexpr int kR   = 256;
constexpr int kD   = 64;
constexpr int kDV  = 64;

constexpr int kChunks  = 4;     // 64-col chunks per block
constexpr int kABlocks = 256;   // 256 cols each
constexpr int kBBlocks = 256;   // 256 cols each
constexpr int kRBlocks = 128;   // 128 outputs each, sums 256 slices

constexpr float kBc   = 0.7745966692414834f;      // sqrt(0.6)
constexpr float kBase0 = -1.1417405264f;          // 0.1 + ln(0.6^16 * 2^10)
constexpr float kOutScale = 9.5367431640625e-7f;  // 2^-20 undoes PHI_SCALE^2
}

// ---------------------------------------------------------------------------
// Kernel A: partials[blk][dv][r] (f16) = (phi(K_cols)*2^10 @ V_cols)^T
// Single barrier per chunk: {pv(c-1) | zphi(c) | stage(c+1) | issue(c+2)} BAR
// sPhi double-buffered, sVt triple-buffered.
// ---------------------------------------------------------------------------
__global__ __launch_bounds__(512, 2)
void favor_kv(const float* __restrict__ Kg, const float* __restrict__ Vg,
              const float* __restrict__ Wg, f16* __restrict__ partials)
{
    __shared__ f16 sXt[2][64 * 64];    // K chunk [l][d], swizzled, dbuf
    __shared__ f16 sVt[3][64 * 64];    // V chunk [dv][l], swizzled, 3-buf
    __shared__ f16 sPhi[2][256 * 64];  // [r][l], swizzled, dbuf
    __shared__ float sRed[2][8 * 64];
    __shared__ float sRedT[2][64];

    const int tid  = threadIdx.x;
    const int w    = tid >> 6;
    const int lane = tid & 63;
    const int l15  = lane & 15;
    const int lhi  = lane >> 4;
    const int blk  = blockIdx.x;
    const int lblk = blk * (64 * kChunks);

    const int scol  = lane;
    const int dbase = w * 8;
    const int wr = w >> 1;
    const int wc = w & 1;

    // rolling register buffers (depth 2)
    float ka[2][8], va[2][8];
    auto issueLoads = [&](int c) {
        const int l0 = lblk + c * 64;
        const int p  = c & 1;
#pragma unroll
        for (int j = 0; j < 8; ++j) ka[p][j] = Kg[(dbase + j) * kL + l0 + scol];
#pragma unroll
        for (int j = 0; j < 8; ++j) va[p][j] = Vg[(size_t)(l0 + dbase + j) * kDV + scol];
    };

    issueLoads(0);
    issueLoads(1);

    f16x8 wfrag[2][2];  // B-operand: col = l15 -> r, k = 8*lhi+j -> d
#pragma unroll
    for (int ri = 0; ri < 2; ++ri)
#pragma unroll
        for (int ks = 0; ks < 2; ++ks) {
            const float* p = Wg + (32 * w + 16 * ri + l15) * kD + 32 * ks + 8 * lhi;
            f16x8 v;
#pragma unroll
            for (int j = 0; j < 8; ++j) v[j] = (f16)p[j];
            wfrag[ri][ks] = v;
        }

    f32x4 acc[4][2];
#pragma unroll
    for (int a = 0; a < 4; ++a)
#pragma unroll
        for (int d = 0; d < 2; ++d) { f32x4 z0 = {0.f, 0.f, 0.f, 0.f}; acc[a][d] = z0; }

    auto stage = [&](int c) {
        const int p  = c & 1;
        const int pv3 = c % 3;
        float s = 0.f;
        f16x8 hk, hv;
#pragma unroll
        for (int j = 0; j < 8; ++j) {
            const float x = ka[p][j];
            s += x * x;
            hk[j] = (f16)x;
            hv[j] = (f16)va[p][j];
        }
        sRed[p][w * 64 + scol] = s;
        *(f16x8*)&sXt[p][scol * 64 + (dbase ^ ((scol & 7) << 3))] = hk;
        *(f16x8*)&sVt[pv3][scol * 64 + (dbase ^ ((scol & 7) << 3))] = hv;
    };

    auto norms = [&](int c) {
        const int p = c & 1;
        float sqv = 0.f;
#pragma unroll
        for (int g = 0; g < 8; ++g) sqv += sRed[p][g * 64 + lane];
        sRedT[p][lane] = sqv;
    };

    auto zphi = [&](int c) {
        const int p = c & 1;
        f16x8 bfr[2][4];
#pragma unroll
        for (int ks = 0; ks < 2; ++ks)
#pragma unroll
            for (int lf = 0; lf < 4; ++lf) {
                const int row = 16 * lf + l15;
                bfr[ks][lf] = *(const f16x8*)&sXt[p][row * 64 + ((32 * ks + 8 * lhi) ^ ((row & 7) << 3))];
            }
#pragma unroll
        for (int ri = 0; ri < 2; ++ri) {
            f32x4 z[4];
#pragma unroll
            for (int lf = 0; lf < 4; ++lf) { f32x4 z0 = {0.f, 0.f, 0.f, 0.f}; z[lf] = z0; }
            __builtin_amdgcn_s_setprio(1);
#pragma unroll
            for (int ks = 0; ks < 2; ++ks)
#pragma unroll
                for (int lf = 0; lf < 4; ++lf)
                    z[lf] = __builtin_amdgcn_mfma_f32_16x16x32_f16(bfr[ks][lf], wfrag[ri][ks], z[lf], 0, 0, 0);
            __builtin_amdgcn_s_setprio(0);
            const int r = 32 * w + 16 * ri + l15;
#pragma unroll
            for (int lf = 0; lf < 4; ++lf) {
                const f32x4 sq4 = *(const f32x4*)&sRedT[p][16 * lf + 4 * lhi];
                f16x4 ph;
#pragma unroll
                for (int j = 0; j < 4; ++j)
                    ph[j] = (f16)__expf(fmaf(z[lf][j], kBc, kBase0 - sq4[j]));
                const int lbase = 16 * lf + 4 * lhi;
                *(f16x4*)&sPhi[p][r * 64 + (lbase ^ ((r & 7) << 3))] = ph;
            }
        }
    };

    auto pv = [&](int c) {
        const int p  = c & 1;
        const int pv3 = c % 3;
        __builtin_amdgcn_s_setprio(1);
#pragma unroll
        for (int ks = 0; ks < 2; ++ks) {
            f16x8 af[4], bf[2];
#pragma unroll
            for (int ai = 0; ai < 4; ++ai) {
                const int r = 64 * wr + 16 * ai + l15;
                af[ai] = *(const f16x8*)&sPhi[p][r * 64 + ((32 * ks + 8 * lhi) ^ ((r & 7) << 3))];
            }
#pragma unroll
            for (int di = 0; di < 2; ++di) {
                const int dv = 32 * wc + 16 * di + l15;
                bf[di] = *(const f16x8*)&sVt[pv3][dv * 64 + ((32 * ks + 8 * lhi) ^ ((dv & 7) << 3))];
            }
#pragma unroll
            for (int ai = 0; ai < 4; ++ai)
#pragma unroll
                for (int di = 0; di < 2; ++di)
                    acc[ai][di] = __builtin_amdgcn_mfma_f32_16x16x32_f16(af[ai], bf[di], acc[ai][di], 0, 0, 0);
        }
        __builtin_amdgcn_s_setprio(0);
    };

    stage(0);
    BARRIER();
#pragma unroll
    for (int c = 0; c < kChunks; ++c) {
        if (c > 0) pv(c - 1);
        norms(c);
        zphi(c);
        if (c + 1 < kChunks) stage(c + 1);
        if (c + 2 < kChunks) issueLoads(c + 2);
        BARRIER();
    }
    pv(kChunks - 1);

    // ---- per-block partial, stored TRANSPOSED [dv][r]
    f16* po = partials + (size_t)blk * (kR * kDV);
#pragma unroll
    for (int ai = 0; ai < 4; ++ai)
#pragma unroll
        for (int di = 0; di < 2; ++di) {
            const int dv = 32 * wc + 16 * di + l15;
            f16x4 pk;
#pragma unroll
            for (int j = 0; j < 4; ++j) pk[j] = (f16)acc[ai][di][j];
            *(f16x4*)&po[dv * kR + 64 * wr + 16 * ai + 4 * lhi] = pk;
        }
}

// ---------------------------------------------------------------------------
// Kernel R: kvT[o] = sum over 256 slices of partials[s][o]  (o = dv*256 + r)
// Block 0 also packs W into f16 fragment order (Wp) for kernel B.
// ---------------------------------------------------------------------------
__global__ __launch_bounds__(512)
void favor_reduce(const f16* __restrict__ partials, f16* __restrict__ kvT,
                  const float* __restrict__ Wg, f16* __restrict__ Wp)
{
    __shared__ float sAcc[32][128];
    const int tid  = threadIdx.x;
    const int slot = tid & 15;
    const int g    = tid >> 4;

    if (blockIdx.x == 0) {
#pragma unroll
        for (int it = 0; it < 4; ++it) {
            const int idx    = tid + it * 512;      // 0..2047
            const int fragid = idx >> 6;            // rf*2+ks
            const int ln     = idx & 63;
            const int rf = fragid >> 1, ks = fragid & 1;
            const float* src = Wg + (16 * rf + (ln & 15)) * kD + 32 * ks + 8 * (ln >> 4);
            f16x8 v;
#pragma unroll
            for (int j = 0; j < 8; ++j) v[j] = (f16)src[j];
            *(f16x8*)&Wp[(size_t)idx * 8] = v;
        }
    }

    const size_t obase = (size_t)blockIdx.x * 128 + slot * 8;
    float a[8] = {0.f, 0.f, 0.f, 0.f, 0.f, 0.f, 0.f, 0.f};
#pragma unroll 4
    for (int i = 0; i < 8; ++i) {
        const int s = g * 8 + i;
        const f16x8 v = *(const f16x8*)&partials[(size_t)s * (kR * kDV) + obase];
#pragma unroll
        for (int j = 0; j < 8; ++j) a[j] += (float)v[j];
    }
#pragma unroll
    for (int j = 0; j < 8; ++j) sAcc[g][slot * 8 + j] = a[j];
    __syncthreads();

    if (tid < 128) {
        float tot = 0.f;
#pragma unroll
        for (int gg = 0; gg < 32; ++gg) tot += sAcc[gg][tid];
        kvT[(size_t)blockIdx.x * 128 + tid] = (f16)tot;
    }
}

// ---------------------------------------------------------------------------
// Kernel B: out = (phi(Q)*2^10)^T @ kv, scaled 2^-20.
// Single barrier per chunk: {pvOut(c-1) | zphiQ(c) | stageQ(c+1) | issue(c+2)} BAR
// sPhiT double-buffered; kv register-resident; W via Wp.
// ---------------------------------------------------------------------------
__global__ __launch_bounds__(512, 2)
void favor_out(const float* __restrict__ Qg, const f16* __restrict__ Wp,
               const f16* __restrict__ kvT, float* __restrict__ outg)
{
    __shared__ f16 sXt[2][64 * 64];    // Q chunk [l][d], swizzled, dbuf
    __shared__ f16 sPhiT[2][64 * 256]; // [l][r], swizzled, dbuf
    __shared__ float sRed[2][8 * 64];

    const int tid  = threadIdx.x;
    const int w    = tid >> 6;
    const int lane = tid & 63;
    const int l15  = lane & 15;
    const int lhi  = lane >> 4;
    const int blk  = blockIdx.x;
    const int lblk = blk * (64 * kChunks);

    const int scol  = lane;
    const int dbase = w * 8;
    const int lfo = w >> 1;
    const int dvh = w & 1;

    float qa[2][8];
    auto issueLoads = [&](int c) {
        const int l0 = lblk + c * 64;
        const int p  = c & 1;
#pragma unroll
        for (int j = 0; j < 8; ++j) qa[p][j] = Qg[(dbase + j) * kL + l0 + scol];
    };

    issueLoads(0);
    issueLoads(1);

    f16x8 kvf[2][8];  // B-operand: rows dv, k = r
#pragma unroll
    for (int di = 0; di < 2; ++di) {
        const int dv = 32 * dvh + 16 * di + l15;
#pragma unroll
        for (int ks = 0; ks < 8; ++ks)
            kvf[di][ks] = *(const f16x8*)&kvT[dv * kR + 32 * ks + 8 * lhi];
    }

    f16x8 wfrag[2][2];  // A-operand for wave w's r rows 32w+16ri (packed)
#pragma unroll
    for (int ri = 0; ri < 2; ++ri)
#pragma unroll
        for (int ks = 0; ks < 2; ++ks)
            wfrag[ri][ks] = *(const f16x8*)&Wp[(size_t)((((2 * w + ri) * 2 + ks) * 64) + lane) * 8];

    auto stageQ = [&](int c) {
        const int p = c & 1;
        float s = 0.f;
        f16x8 hq;
#pragma unroll
        for (int j = 0; j < 8; ++j) {
            const float x = qa[p][j];
            s += x * x;
            hq[j] = (f16)x;
        }
        sRed[p][w * 64 + scol] = s;
        *(f16x8*)&sXt[p][scol * 64 + (dbase ^ ((scol & 7) << 3))] = hq;
    };

    auto zphiQ = [&](int c) {
        const int p = c & 1;
        float sqv = 0.f;
#pragma unroll
        for (int g = 0; g < 8; ++g) sqv += sRed[p][g * 64 + lane];
        float tbase[4];
#pragma unroll
        for (int lf = 0; lf < 4; ++lf)
            tbase[lf] = kBase0 - __shfl(sqv, lf * 16 + l15, 64);

        f16x8 bfr[2][4];
#pragma unroll
        for (int ks = 0; ks < 2; ++ks)
#pragma unroll
            for (int lf = 0; lf < 4; ++lf) {
                const int row = 16 * lf + l15;
                bfr[ks][lf] = *(const f16x8*)&sXt[p][row * 64 + ((32 * ks + 8 * lhi) ^ ((row & 7) << 3))];
            }
#pragma unroll
        for (int ri = 0; ri < 2; ++ri) {
            f32x4 z[4];
#pragma unroll
            for (int lf = 0; lf < 4; ++lf) { f32x4 z0 = {0.f, 0.f, 0.f, 0.f}; z[lf] = z0; }
            __builtin_amdgcn_s_setprio(1);
#pragma unroll
            for (int ks = 0; ks < 2; ++ks)
#pragma unroll
                for (int lf = 0; lf < 4; ++lf)
                    z[lf] = __builtin_amdgcn_mfma_f32_16x16x32_f16(wfrag[ri][ks], bfr[ks][lf], z[lf], 0, 0, 0);
            __builtin_amdgcn_s_setprio(0);
            const int r0 = 32 * w + 16 * ri + 4 * lhi;
#pragma unroll
            for (int lf = 0; lf < 4; ++lf) {
                const int lc = 16 * lf + l15;
                f16x4 ph;
#pragma unroll
                for (int j = 0; j < 4; ++j)
                    ph[j] = (f16)__expf(fmaf(z[lf][j], kBc, tbase[lf]));
                *(f16x4*)&sPhiT[p][lc * 256 + (r0 ^ ((lc & 7) << 3))] = ph;
            }
        }
    };

    auto pvOut = [&](int c) {
        const int p = c & 1;
        f32x4 oA[2], oB[2];
        { f32x4 z0 = {0.f, 0.f, 0.f, 0.f}; oA[0] = z0; oA[1] = z0; oB[0] = z0; oB[1] = z0; }
        const int lrow = 16 * lfo + l15;
        __builtin_amdgcn_s_setprio(1);
#pragma unroll
        for (int ks = 0; ks < 4; ++ks) {
            const f16x8 afA = *(const f16x8*)&sPhiT[p][lrow * 256 + ((32 * ks + 8 * lhi) ^ ((lrow & 7) << 3))];
            const f16x8 afB = *(const f16x8*)&sPhiT[p][lrow * 256 + ((32 * (ks + 4) + 8 * lhi) ^ ((lrow & 7) << 3))];
#pragma unroll
            for (int di = 0; di < 2; ++di) {
                oA[di] = __builtin_amdgcn_mfma_f32_16x16x32_f16(afA, kvf[di][ks], oA[di], 0, 0, 0);
                oB[di] = __builtin_amdgcn_mfma_f32_16x16x32_f16(afB, kvf[di][ks + 4], oB[di], 0, 0, 0);
            }
        }
        __builtin_amdgcn_s_setprio(0);
        const int l0 = lblk + c * 64;
#pragma unroll
        for (int di = 0; di < 2; ++di) {
            const f32x4 o2 = oA[di] + oB[di];
#pragma unroll
            for (int j = 0; j < 4; ++j) {
                const int ll = 16 * lfo + 4 * lhi + j;
                const int dv = 32 * dvh + 16 * di + l15;
                outg[(size_t)(l0 + ll) * kDV + dv] = o2[j] * kOutScale;
            }
        }
    };

    stageQ(0);
    BARRIER();
#pragma unroll
    for (int c = 0; c < kChunks; ++c) {
        if (c > 0) pvOut(c - 1);
        zphiQ(c);
        if (c + 1 < kChunks) stageQ(c + 1);
        if (c + 2 < kChunks) issueLoads(c + 2);
        BARRIER();
    }
    pvOut(kChunks - 1);
}

extern "C" void kernel_launch(void* const* d_in, const int* in_sizes, int n_in,
                              void* d_out, int out_size, void* d_ws, size_t ws_size,
                              hipStream_t stream)
{
    const float* Q = (const float*)d_in[0];
    const float* K = (const float*)d_in[1];
    const float* V = (const float*)d_in[2];
    const float* W = (const float*)d_in[3];
    float* out = (float*)d_out;

    f16* partials = (f16*)d_ws;  // 256 * 16384 f16 = 8 MiB
    f16* kvT = (f16*)((char*)d_ws + (size_t)kABlocks * kR * kDV * sizeof(f16));
    f16* Wp  = kvT + (size_t)kR * kDV;  // 32 KiB packed W

    favor_kv<<<kABlocks, 512, 0, stream>>>(K, V, W, partials);
    favor_reduce<<<kRBlocks, 512, 0, stream>>>(partials, kvT, W, Wp);
    favor_out<<<kBBlocks, 512, 0, stream>>>(Q, Wp, kvT, out);

    (void)in_sizes; (void)n_in; (void)out_size; (void)ws_size;
}